// Round 2
// baseline (156.717 us; speedup 1.0000x reference)
//
#include <hip/hip_runtime.h>

// Segment-mean of x[:,0] over sorted segment ids b, n_graphs bins.
// Strategy: wave-aggregated atomics (b sorted => waves are nearly always
// segment-uniform), then a tiny divide kernel.

__global__ void seg_reduce_kernel(const float* __restrict__ x,
                                  const int* __restrict__ b,
                                  float* __restrict__ sums,
                                  float* __restrict__ cnts,
                                  int n, int nfeat) {
    int idx = blockIdx.x * blockDim.x + threadIdx.x;
    int stride = gridDim.x * blockDim.x;
    // n % 64 == 0 and idx bases are wave-aligned, so every wave iteration is
    // either fully active or fully inactive -> shuffles/__all are safe.
    for (int i = idx; i < n; i += stride) {
        float v = x[(size_t)i * (size_t)nfeat];   // column 0, stride-nfeat read
        int seg = b[i];
        int first_seg = __shfl(seg, 0, 64);
        if (__all(seg == first_seg)) {
            // whole wave in one segment: tree-reduce then 1 atomic pair
            float s = v;
            #pragma unroll
            for (int off = 32; off > 0; off >>= 1)
                s += __shfl_down(s, off, 64);
            if ((threadIdx.x & 63) == 0) {
                atomicAdd(&sums[seg], s);
                atomicAdd(&cnts[seg], 64.0f);
            }
        } else {
            // boundary wave (rare: ~13% of waves, <=2 segments each)
            atomicAdd(&sums[seg], v);
            atomicAdd(&cnts[seg], 1.0f);
        }
    }
}

__global__ void divide_kernel(const float* __restrict__ sums,
                              const float* __restrict__ cnts,
                              float* __restrict__ out, int ng) {
    int g = blockIdx.x * blockDim.x + threadIdx.x;
    if (g < ng) out[g] = sums[g] / cnts[g];
}

extern "C" void kernel_launch(void* const* d_in, const int* in_sizes, int n_in,
                              void* d_out, int out_size, void* d_ws, size_t ws_size,
                              hipStream_t stream) {
    const float* x = (const float*)d_in[0];
    const int*   b = (const int*)d_in[1];
    int n     = in_sizes[1];              // 2,000,000 nodes
    int nfeat = in_sizes[0] / n;          // 64
    int ng    = out_size;                 // 4096 graphs

    float* sums = (float*)d_ws;
    float* cnts = sums + ng;

    // zero the accumulators (graph-capture-safe async memset)
    hipMemsetAsync(d_ws, 0, (size_t)2 * (size_t)ng * sizeof(float), stream);

    const int block = 256;
    int grid = (n + block - 1) / block;
    if (grid > 2048) grid = 2048;         // grid-stride; ~8 blocks/CU
    seg_reduce_kernel<<<grid, block, 0, stream>>>(x, b, sums, cnts, n, nfeat);

    divide_kernel<<<(ng + 255) / 256, 256, 0, stream>>>(sums, cnts, (float*)d_out, ng);
}

// Round 3
// 73.440 us; speedup vs baseline: 2.1340x; 2.1340x over previous
//
#include <hip/hip_runtime.h>

// Segment-mean of x[:,0] (row stride nfeat=64) over sorted ids b, ng bins.
// R2 strategy: per-thread contiguous 16-node chunk -> 16 independent strided
// loads (deep MLP), segment-uniform fast path (1 atomic per chunk), counts via
// binary search (no count atomics), then divide.

constexpr int K = 16;

__global__ void seg_sum_kernel(const float* __restrict__ x,
                               const int* __restrict__ b,
                               float* __restrict__ sums,
                               int n, int nfeat) {
    int t = blockIdx.x * blockDim.x + threadIdx.x;
    long long base = (long long)t * K;
    if (base + K > n) {
        // scalar tail (never taken for n % 16 == 0, kept for safety)
        for (long long i = base; i < n; ++i)
            atomicAdd(&sums[b[i]], x[(size_t)i * nfeat]);
        return;
    }

    // Issue all loads up-front: 16 independent column-0 loads + 4x int4 of b.
    const float* xp = x + (size_t)base * nfeat;
    float v[K];
#pragma unroll
    for (int u = 0; u < K; ++u) v[u] = xp[(size_t)u * nfeat];
    int4 q0 = *reinterpret_cast<const int4*>(b + base);
    int4 q1 = *reinterpret_cast<const int4*>(b + base + 4);
    int4 q2 = *reinterpret_cast<const int4*>(b + base + 8);
    int4 q3 = *reinterpret_cast<const int4*>(b + base + 12);

    if (q0.x == q3.w) {
        // whole chunk in one segment (b sorted): pairwise tree sum, 1 atomic
        float acc = (((v[0] + v[1]) + (v[2] + v[3])) + ((v[4] + v[5]) + (v[6] + v[7])))
                  + (((v[8] + v[9]) + (v[10] + v[11])) + ((v[12] + v[13]) + (v[14] + v[15])));
        atomicAdd(&sums[q0.x], acc);
    } else {
        // boundary chunk (~3%): unrolled constant-index scan, stays in regs
        int sv[K] = {q0.x, q0.y, q0.z, q0.w, q1.x, q1.y, q1.z, q1.w,
                     q2.x, q2.y, q2.z, q2.w, q3.x, q3.y, q3.z, q3.w};
        float acc = 0.f;
        int cur = sv[0];
#pragma unroll
        for (int u = 0; u < K; ++u) {
            if (sv[u] != cur) { atomicAdd(&sums[cur], acc); acc = 0.f; cur = sv[u]; }
            acc += v[u];
        }
        atomicAdd(&sums[cur], acc);
    }
}

__global__ void mean_kernel(const float* __restrict__ sums,
                            const int* __restrict__ b,
                            float* __restrict__ out, int n, int ng) {
    int g = blockIdx.x * blockDim.x + threadIdx.x;
    if (g >= ng) return;
    // count[g] = upper_bound(g) - lower_bound(g) in sorted b (L2/L3-resident)
    int lo = 0, hi = n;
    while (lo < hi) { int m = (lo + hi) >> 1; if (b[m] <  g) lo = m + 1; else hi = m; }
    int lb = lo;
    lo = 0; hi = n;
    while (lo < hi) { int m = (lo + hi) >> 1; if (b[m] <= g) lo = m + 1; else hi = m; }
    out[g] = sums[g] / (float)(lo - lb);
}

extern "C" void kernel_launch(void* const* d_in, const int* in_sizes, int n_in,
                              void* d_out, int out_size, void* d_ws, size_t ws_size,
                              hipStream_t stream) {
    const float* x = (const float*)d_in[0];
    const int*   b = (const int*)d_in[1];
    int n     = in_sizes[1];              // 2,000,000 nodes
    int nfeat = in_sizes[0] / n;          // 64
    int ng    = out_size;                 // 4096 graphs

    float* sums = (float*)d_ws;
    hipMemsetAsync(d_ws, 0, (size_t)ng * sizeof(float), stream);

    int threads = (n + K - 1) / K;        // 125,000
    const int block = 256;
    int grid = (threads + block - 1) / block;
    seg_sum_kernel<<<grid, block, 0, stream>>>(x, b, sums, n, nfeat);

    mean_kernel<<<(ng + 255) / 256, 256, 0, stream>>>(sums, b, (float*)d_out, n, ng);
}

// Round 4
// 47.458 us; speedup vs baseline: 3.3022x; 1.5475x over previous
//
#include <hip/hip_runtime.h>

// Segment-mean of x[:,0] (row stride nfeat) over sorted ids b, ng bins.
// R3: single kernel, one block per graph. Two concurrent binary searches
// (wave 0 / wave 1) find [lb, ub); block-strided gather + reduce; direct
// out[g] write. No atomics, no workspace, no memset, one launch.

__global__ void seg_mean_kernel(const float* __restrict__ x,
                                const int* __restrict__ b,
                                float* __restrict__ out,
                                int n, int nfeat) {
    int g = blockIdx.x;
    __shared__ int s_lb, s_ub;
    __shared__ float s_part[4];

    if (threadIdx.x == 0) {
        // lower_bound(g)
        int lo = 0, hi = n;
        while (lo < hi) { int m = (lo + hi) >> 1; if (b[m] < g) lo = m + 1; else hi = m; }
        s_lb = lo;
    }
    if (threadIdx.x == 64) {
        // upper_bound(g) — runs in a different wave, concurrently with lower_bound
        int lo = 0, hi = n;
        while (lo < hi) { int m = (lo + hi) >> 1; if (b[m] <= g) lo = m + 1; else hi = m; }
        s_ub = lo;
    }
    __syncthreads();
    int lb = s_lb, ub = s_ub;

    // block-strided gather of column 0 (one cache line per node, unavoidable)
    float acc = 0.f;
    for (int i = lb + (int)threadIdx.x; i < ub; i += (int)blockDim.x)
        acc += x[(size_t)i * (size_t)nfeat];

    // wave reduce (64 lanes)
    #pragma unroll
    for (int off = 32; off > 0; off >>= 1)
        acc += __shfl_down(acc, off, 64);
    if ((threadIdx.x & 63) == 0) s_part[threadIdx.x >> 6] = acc;
    __syncthreads();

    if (threadIdx.x == 0) {
        float s = s_part[0] + s_part[1] + s_part[2] + s_part[3];
        out[g] = s / (float)(ub - lb);
    }
}

extern "C" void kernel_launch(void* const* d_in, const int* in_sizes, int n_in,
                              void* d_out, int out_size, void* d_ws, size_t ws_size,
                              hipStream_t stream) {
    const float* x = (const float*)d_in[0];
    const int*   b = (const int*)d_in[1];
    int n     = in_sizes[1];              // 2,000,000 nodes
    int nfeat = in_sizes[0] / n;          // 64
    int ng    = out_size;                 // 4096 graphs

    seg_mean_kernel<<<ng, 256, 0, stream>>>(x, b, (float*)d_out, n, nfeat);
}

// Round 5
// 46.058 us; speedup vs baseline: 3.4026x; 1.0304x over previous
//
#include <hip/hip_runtime.h>

// Segment-mean of x[:,0] (row stride nfeat) over sorted ids b, ng bins.
// R4: one block per graph. 64-ary wave-parallel lower_bound (wave0: lb(g),
// wave1: lb(g+1)) -> ~5 wide probes instead of 21 dependent ones. Gather uses
// non-temporal loads (zero reuse; try for 64B fetch granularity) with a 2x
// unroll so both loads are in flight together. No atomics, no workspace.

__device__ __forceinline__ int lower_bound_wide(const int* __restrict__ b, int n,
                                                int target, int lane) {
    // invariant: answer in [lo, hi]; loop is wave-uniform (lo/hi from ballot)
    int lo = 0, hi = n;
    while (hi > lo) {
        long long span = (long long)(hi - lo);
        int q = lo + (int)((span * lane) >> 6);      // 64 evenly spaced probes
        int v = b[q];
        unsigned long long m = __ballot(v < target);
        if (m == 0ULL) return lo;                    // b[lo] >= target
        int k = 63 - __clzll(m);                     // highest probe below target
        int qk  = lo + (int)((span * (long long)k) >> 6);
        int qk1 = (k < 63) ? (lo + (int)((span * (long long)(k + 1)) >> 6)) : hi;
        lo = qk + 1;
        hi = qk1;
    }
    return lo;
}

__global__ __launch_bounds__(256)
void seg_mean_kernel(const float* __restrict__ x,
                     const int* __restrict__ b,
                     float* __restrict__ out,
                     int n, int nfeat) {
    int g = blockIdx.x;
    int lane = threadIdx.x & 63;
    int wave = threadIdx.x >> 6;
    __shared__ int s_lb, s_ub;
    __shared__ float s_part[4];

    if (wave == 0) {
        int r = lower_bound_wide(b, n, g, lane);
        if (lane == 0) s_lb = r;
    } else if (wave == 1) {
        int r = lower_bound_wide(b, n, g + 1, lane);   // upper bound of g
        if (lane == 0) s_ub = r;
    }
    __syncthreads();
    int lb = s_lb, ub = s_ub;

    // gather column 0: one cache line per node, zero reuse -> non-temporal.
    // 2x unroll so both loads issue before either s_waitcnt.
    float acc = 0.f;
    int i0 = lb + (int)threadIdx.x;
    int stride = (int)blockDim.x;
    for (; i0 + stride < ub; i0 += 2 * stride) {
        float v0 = __builtin_nontemporal_load(x + (size_t)i0 * (size_t)nfeat);
        float v1 = __builtin_nontemporal_load(x + (size_t)(i0 + stride) * (size_t)nfeat);
        acc += v0 + v1;
    }
    if (i0 < ub)
        acc += __builtin_nontemporal_load(x + (size_t)i0 * (size_t)nfeat);

    // wave reduce then cross-wave combine
    #pragma unroll
    for (int off = 32; off > 0; off >>= 1)
        acc += __shfl_down(acc, off, 64);
    if (lane == 0) s_part[wave] = acc;
    __syncthreads();

    if (threadIdx.x == 0) {
        float s = s_part[0] + s_part[1] + s_part[2] + s_part[3];
        out[g] = s / (float)(ub - lb);
    }
}

extern "C" void kernel_launch(void* const* d_in, const int* in_sizes, int n_in,
                              void* d_out, int out_size, void* d_ws, size_t ws_size,
                              hipStream_t stream) {
    const float* x = (const float*)d_in[0];
    const int*   b = (const int*)d_in[1];
    int n     = in_sizes[1];              // 2,000,000 nodes
    int nfeat = in_sizes[0] / n;          // 64
    int ng    = out_size;                 // 4096 graphs

    seg_mean_kernel<<<ng, 256, 0, stream>>>(x, b, (float*)d_out, n, nfeat);
}